// Round 8
// baseline (738.402 us; speedup 1.0000x reference)
//
#include <hip/hip_runtime.h>

typedef __attribute__((ext_vector_type(8))) short bf16x8;
typedef __attribute__((ext_vector_type(4))) float f32x4;

#define SL 2048
#define DM 768
#define MSPEC 24576   /* 32*768 */
#define MTOT  26880   /* 24576 + 3*768 */
#define CNT_OFF 171311104

__device__ __forceinline__ short f2bf(float f) {
  unsigned u = __builtin_bit_cast(unsigned, f);
  u = (u + 0x7FFFu + ((u >> 16) & 1u)) >> 16;
  return (short)u;
}

// async global->LDS, 16B per lane. LDS dest must be wave-uniform base + lane*16.
__device__ __forceinline__ void gload16(const short* g, short* l) {
  __builtin_amdgcn_global_load_lds(
      (const __attribute__((address_space(1))) void*)g,
      (__attribute__((address_space(3))) void*)l, 16, 0, 0);
}

// ---------------- front: ALL prep in one launch (pure-BW work fused together) ----------------
// [0,5040) prep_M | [5040,6576) zero out (+cnt) | [6576,6960) xT | [6960,11056) Tmat | [11056,13360) AR
__global__ __launch_bounds__(256) void k_front(const float* __restrict__ x,
                                               const float* __restrict__ phi,
                                               const float* __restrict__ Mp,
                                               const float* __restrict__ Mm,
                                               const float* __restrict__ Mu,
                                               const float* __restrict__ sigma,
                                               float* __restrict__ out,
                                               short* __restrict__ xT,
                                               short* __restrict__ Tmat,
                                               short* __restrict__ U,
                                               short* __restrict__ McatT,
                                               unsigned* __restrict__ cnt) {
  __shared__ short tile[64 * 65];
  const int wid = blockIdx.x;
  const int t = threadIdx.x;

  if (wid < 5040) {                       // ---- McatT[o][m] (sigma^(1/4)-scaled proj + M_u)
    const int m0 = (wid % 420) * 64, o0 = (wid / 420) * 64;
#pragma unroll
    for (int rr = 0; rr < 16; ++rr) {
      int ml = rr * 4 + (t >> 6), ol = t & 63;
      int m = m0 + ml, o = o0 + ol;
      float v;
      if (m < MSPEC) {
        int c = m / DM, d = m - c * DM;
        int k = c & 15;
        float s4 = sqrtf(sqrtf(sigma[k]));
        if (c < 16) v = Mp[((size_t)c * DM + d) * DM + o] * s4;
        else        v = Mm[((size_t)(c - 16) * DM + d) * DM + o] * s4;
      } else {
        int mm = m - MSPEC;
        int i = mm / DM, d = mm - i * DM;
        v = Mu[((size_t)i * DM + d) * DM + o];
      }
      tile[ml * 65 + ol] = f2bf(v);
    }
    __syncthreads();
#pragma unroll
    for (int rr = 0; rr < 16; ++rr) {
      int ol = rr * 4 + (t >> 6), ml = t & 63;
      McatT[(size_t)(o0 + ol) * MTOT + m0 + ml] = tile[ml * 65 + ol];
    }

  } else if (wid < 6576) {                // ---- zero out (6.3 MB) + zero counters
    const int w2 = wid - 5040;
    if (w2 == 0 && t < 16) cnt[t] = 0u;
    reinterpret_cast<float4*>(out)[(size_t)w2 * 256 + t] = float4{0.f, 0.f, 0.f, 0.f};

  } else if (wid < 6960) {                // ---- xT[d][l] = bf16(x[l][d])
    const int b = wid - 6576;
    const int d0 = (b % 12) * 64, l0 = (b / 12) * 64;
#pragma unroll
    for (int rr = 0; rr < 16; ++rr) {
      int ll = rr * 4 + (t >> 6), dl = t & 63;
      tile[ll * 65 + dl] = f2bf(x[(size_t)(l0 + ll) * DM + d0 + dl]);
    }
    __syncthreads();
#pragma unroll
    for (int rr = 0; rr < 16; ++rr) {
      int dl = rr * 4 + (t >> 6), ll = t & 63;
      xT[(size_t)(d0 + dl) * SL + l0 + ll] = tile[ll * 65 + dl];
    }

  } else if (wid < 11056) {               // ---- Tmat[c][dlag][a][b] = f_c[dlag*128+a-b], 8/thread
    int g = (wid - 6960) * 256 + t;       // 0..1048575
    int b8 = g & 15, a = (g >> 4) & 127, dlag = (g >> 11) & 15, c = g >> 15;
    int k = c & 15;
    int jb = dlag * 128 + a - b8 * 8;
    short v[8];
#pragma unroll
    for (int i2 = 0; i2 < 8; ++i2) {
      int j = jb - i2;
      float p = 0.f;
      if (j >= 0) {
        p = phi[j * 16 + k];
        if (c >= 16 && (j & 1)) p = -p;
      }
      v[i2] = f2bf(p);
    }
    *reinterpret_cast<int4*>(Tmat + (size_t)g * 8) = *reinterpret_cast<const int4*>(v);

  } else {                                // ---- AR cols: U[l][MSPEC+i*768+d] = x[l-i][d], 8/thread
    int g = (wid - 11056) * 256 + t;      // 0..589823
    int d8 = g % 96;
    int rest = g / 96;                    // i*2048 + l
    int l = rest & 2047, i = rest >> 11;  // i in 0..2
    int d = d8 * 8;
    short v[8] = {0, 0, 0, 0, 0, 0, 0, 0};
    if (l >= i) {
      const float4* src = reinterpret_cast<const float4*>(x + (size_t)(l - i) * DM + d);
      float4 f0 = src[0], f1 = src[1];
      v[0] = f2bf(f0.x); v[1] = f2bf(f0.y); v[2] = f2bf(f0.z); v[3] = f2bf(f0.w);
      v[4] = f2bf(f1.x); v[5] = f2bf(f1.y); v[6] = f2bf(f1.z); v[7] = f2bf(f1.w);
    }
    *reinterpret_cast<int4*>(U + (size_t)l * MTOT + MSPEC + i * DM + d) =
        *reinterpret_cast<const int4*>(v);
  }
}

// ---------------- gemm12: gemm1 (0..3071) + gemm2 (3072..3839), counter handshake ----------------
__global__ __launch_bounds__(256) void k_gemm12(const short* __restrict__ Tmat,
                                                const short* __restrict__ xT,
                                                short* __restrict__ U,
                                                const short* __restrict__ McatT,
                                                float* __restrict__ out,
                                                unsigned* __restrict__ cnt) {
  __shared__ __align__(16) short As[2][128 * 32];
  __shared__ __align__(16) short Bs[2][128 * 32];
  const int wid = blockIdx.x;
  const int t = threadIdx.x;
  const int lane = t & 63, wave = t >> 6;
  const int wm = (wave >> 1) * 64, wn = (wave & 1) * 64;
  const int lrow = lane & 15, quad = lane >> 4;
  const int l4 = lane >> 2, lq = lane & 3;
  const int r0 = wave * 32 + l4;
  const int swz = (lq ^ ((l4 >> 1) & 3)) * 8;
  const int foff = ((quad ^ ((lrow >> 1) & 3)) << 3);
  f32x4 acc[4][4] = {};

  if (wid < 3072) {
    // ---------------- gemm1: block-Toeplitz conv (round-3 proven) ----------------
    const int slot = wid >> 3;                 // 0..383
    const int c = (wid & 7) * 4 + (slot & 3);  // 4 channels per XCD
    const int dtile = (slot >> 2) % 6;
    const int ib = 15 - (slot >> 2) / 6;       // big (triangular) blocks first

    const short* Abase = Tmat + (((size_t)c * 16) << 14) + r0 * 128 + swz;
    const short* Bbase = xT + (size_t)dtile * 128 * SL + (size_t)r0 * SL + swz;
    const int nit = 4 * (ib + 1);

    auto stage = [&](int it, int buf) {
      int dlag = it >> 2, kk = it & 3;
      const short* Ad = Abase + ((size_t)dlag << 14) + kk * 32;
      const short* Bd = Bbase + (ib - dlag) * 128 + kk * 32;
      short* lA = &As[buf][wave * 1024 + lane * 8];
      short* lB = &Bs[buf][wave * 1024 + lane * 8];
      gload16(Ad, lA);
      gload16(Ad + 16 * 128, lA + 512);
      gload16(Bd, lB);
      gload16(Bd + 16 * SL, lB + 512);
    };

    stage(0, 0);
    int cur = 0;
    for (int it = 0; it < nit; ++it) {
      __syncthreads();
      if (it + 1 < nit) stage(it + 1, cur ^ 1);
      bf16x8 af[4], bfr[4];
#pragma unroll
      for (int im = 0; im < 4; ++im)
        af[im] = *reinterpret_cast<const bf16x8*>(&As[cur][(wm + im * 16 + lrow) * 32 + foff]);
#pragma unroll
      for (int in = 0; in < 4; ++in)
        bfr[in] = *reinterpret_cast<const bf16x8*>(&Bs[cur][(wn + in * 16 + lrow) * 32 + foff]);
#pragma unroll
      for (int im = 0; im < 4; ++im)
#pragma unroll
        for (int in = 0; in < 4; ++in)
          acc[im][in] = __builtin_amdgcn_mfma_f32_16x16x32_bf16(af[im], bfr[in], acc[im][in], 0, 0, 0);
      cur ^= 1;
    }
    const int l0 = ib * 128, colbase = c * DM + dtile * 128;
#pragma unroll
    for (int im = 0; im < 4; ++im)
#pragma unroll
      for (int in = 0; in < 4; ++in)
#pragma unroll
        for (int r4 = 0; r4 < 4; ++r4) {
          int row = wm + im * 16 + quad * 4 + r4;
          int col = wn + in * 16 + lrow;
          U[(size_t)(l0 + row) * MTOT + colbase + col] = f2bf(acc[im][in][r4]);
        }
    // release: make U writes visible device-wide, then signal
    __syncthreads();
    if (t == 0) {
      __threadfence();
      __hip_atomic_fetch_add(&cnt[ib], 1u, __ATOMIC_RELEASE, __HIP_MEMORY_SCOPE_AGENT);
    }

  } else {
    // ---------------- gemm2: projection + AR, split-K=8 (round-3 proven) ----------------
    const int bid = wid - 3072;                // 0..767
    const int kc = bid & 7;
    const int slot = bid >> 3;                 // 0..95
    const int otile = slot % 6;
    const int lb = 15 - slot / 6;              // high lb first (their gemm1 blocks started first)

    // acquire: wait for all 192 gemm1 blocks of this lb
    if (t == 0) {
      long spins = 0;
      while (__hip_atomic_load(&cnt[lb], __ATOMIC_ACQUIRE, __HIP_MEMORY_SCOPE_AGENT) < 192u) {
        __builtin_amdgcn_s_sleep(32);
        if (++spins > 100000000L) break;   // hang-guard: fail loud, not forever
      }
    }
    __syncthreads();

    const short* Ab = U + (size_t)lb * 128 * MTOT + kc * 3360 + (size_t)r0 * MTOT + swz;
    const short* Bb = McatT + (size_t)otile * 128 * MTOT + kc * 3360 + (size_t)r0 * MTOT + swz;

    auto stage = [&](int s, int buf) {
      short* lA = &As[buf][wave * 1024 + lane * 8];
      short* lB = &Bs[buf][wave * 1024 + lane * 8];
      gload16(Ab + s * 32, lA);
      gload16(Ab + s * 32 + (size_t)16 * MTOT, lA + 512);
      gload16(Bb + s * 32, lB);
      gload16(Bb + s * 32 + (size_t)16 * MTOT, lB + 512);
    };

    stage(0, 0);
    int cur = 0;
    for (int s = 0; s < 105; ++s) {
      __syncthreads();
      if (s + 1 < 105) stage(s + 1, cur ^ 1);
      bf16x8 af[4], bfr[4];
#pragma unroll
      for (int im = 0; im < 4; ++im)
        af[im] = *reinterpret_cast<const bf16x8*>(&As[cur][(wm + im * 16 + lrow) * 32 + foff]);
#pragma unroll
      for (int in = 0; in < 4; ++in)
        bfr[in] = *reinterpret_cast<const bf16x8*>(&Bs[cur][(wn + in * 16 + lrow) * 32 + foff]);
#pragma unroll
      for (int im = 0; im < 4; ++im)
#pragma unroll
        for (int in = 0; in < 4; ++in)
          acc[im][in] = __builtin_amdgcn_mfma_f32_16x16x32_bf16(af[im], bfr[in], acc[im][in], 0, 0, 0);
      cur ^= 1;
    }
    const int l0 = lb * 128, o0 = otile * 128;
#pragma unroll
    for (int im = 0; im < 4; ++im)
#pragma unroll
      for (int in = 0; in < 4; ++in)
#pragma unroll
        for (int r4 = 0; r4 < 4; ++r4) {
          int row = wm + im * 16 + quad * 4 + r4;
          int col = wn + in * 16 + lrow;
          atomicAdd(&out[(size_t)(l0 + row) * DM + o0 + col], acc[im][in][r4]);
        }
  }
}

extern "C" void kernel_launch(void* const* d_in, const int* in_sizes, int n_in,
                              void* d_out, int out_size, void* d_ws, size_t ws_size,
                              hipStream_t stream) {
  (void)in_sizes; (void)n_in; (void)out_size; (void)ws_size;
  const float* x     = (const float*)d_in[0];
  const float* phi   = (const float*)d_in[1];
  const float* sigma = (const float*)d_in[2];
  const float* Mp    = (const float*)d_in[3];
  const float* Mm    = (const float*)d_in[4];
  const float* Mu    = (const float*)d_in[5];
  float* out = (float*)d_out;
  char* ws = (char*)d_ws;

  short* U        = (short*)(ws);                 // 2048*26880*2    = 110,100,480
  short* Tmat     = (short*)(ws + 110100480);     // 32*16*128*128*2 = 16,777,216
  short* xT       = (short*)(ws + 126877696);     // 768*2048*2      = 3,145,728
  short* McatT    = (short*)(ws + 130023424);     // 768*26880*2     = 41,287,680
  unsigned* cnt   = (unsigned*)(ws + CNT_OFF);    // 16 counters (64 B)

  k_front<<<dim3(13360), dim3(256), 0, stream>>>(x, phi, Mp, Mm, Mu, sigma,
                                                 out, xT, Tmat, U, McatT, cnt);
  k_gemm12<<<dim3(3840), dim3(256), 0, stream>>>(Tmat, xT, U, McatT, out, cnt);
}